// Round 12
// baseline (1629.859 us; speedup 1.0000x reference)
//
#include <hip/hip_runtime.h>

// GRU decoder, B=256, H=512, T=512. 16 groups x 16 members = 256 WGs (1/CU).
// Round-12: r11 skeleton + CHECKSUM FLAGS: producer exports data u64s (sc1)
// and immediately stores {tag,xor-csum} per wave per parity -- NO drain, NO
// barrier before the flag. Consumer polls tag (parity-indexed slots), reloads,
// verifies XOR, retries on mismatch (correct under any store completion
// order). Per step: 2 barriers; 2 coherence-point trips on the critical path
// (flag detect, reload) instead of 3 (drain removed).

typedef __attribute__((ext_vector_type(8))) short short8;
typedef __attribute__((ext_vector_type(4))) float f32x4;
typedef __attribute__((ext_vector_type(4))) unsigned int u32x4;
typedef unsigned short ushort_t;
typedef unsigned int uint_t;
typedef unsigned long long u64_t;

#define NG 16
#define NM 16
#define NB 16
#define NJ 32
#define TPB 384
#define POLL_MAX (1u << 14)
#define VERIFY_MAX 4096u
#define ABORT_IDX 8192  // u32 idx (byte 32768), past the 32KB flag region
#define GBUF_BASE 16384 // u32 idx of data region (byte 65536)
#define GRP_U32 4096    // per group per parity: 16 members * 256 u32 (hi only)
#define BUF_U32 65536   // per parity: 16 groups

#define ALD(P) __hip_atomic_load((P), __ATOMIC_RELAXED, __HIP_MEMORY_SCOPE_AGENT)
#define AST(P, V) __hip_atomic_store((P), (V), __ATOMIC_RELAXED, __HIP_MEMORY_SCOPE_AGENT)

__device__ __forceinline__ uint_t fold64(u64_t q) {
  return (uint_t)q ^ (uint_t)(q >> 32);
}
__device__ __forceinline__ ushort_t bf16_rne(float f) {
  uint_t u = __float_as_uint(f);
  return (ushort_t)((u + 0x7fffu + ((u >> 16) & 1u)) >> 16);
}
__device__ __forceinline__ float bf16f(ushort_t h) {
  return __uint_as_float(((uint_t)h) << 16);
}
__device__ __forceinline__ int gRow(int rs, int m) {
  int base = m * NJ;
  if (rs < 32) return base + rs;
  if (rs < 64) return 512 + base + (rs - 32);
  return 1024 + base + (rs - 64);
}

template <bool LO>
__device__ __forceinline__ void loadW(short8* dst, const float* __restrict__ W,
                                      int tile, int m, int lane) {
  int rs = tile * 16 + (lane & 15);
  const float* p = W + (size_t)gRow(rs, m) * 512 + ((lane >> 4) << 3);
#pragma unroll
  for (int c = 0; c < 16; ++c) {
    const float* pc = p + c * 32;
    short8 o;
#pragma unroll
    for (int i = 0; i < 8; ++i) {
      float v = pc[i];
      ushort_t hi = bf16_rne(v);
      o[i] = LO ? (short)bf16_rne(v - bf16f(hi)) : (short)hi;
    }
    dst[c] = o;
  }
}

__global__ __launch_bounds__(TPB, 1) void gru_kernel(
    const float* __restrict__ x, const float* __restrict__ Wih,
    const float* __restrict__ Whh, const float* __restrict__ bih,
    const float* __restrict__ bhh, float* __restrict__ out,
    uint_t* __restrict__ wsp, int NT) {
  __shared__ __align__(16) uint_t s_pb[4096];  // 16KB: 16 chunks x 1KB (hi)
  __shared__ __align__(16) uint_t s_xlo[4096]; // x lo-planes (gi phase only)
  __shared__ float s_gi[96 * 17];
  __shared__ float s_gh[96 * 17];
  __shared__ float s_hloc[NB * NJ]; // own h slice, f32 across steps
  __shared__ float s_bhh[NJ];
  __shared__ int s_stop;

  const int tid = threadIdx.x;
  const int lane = tid & 63;
  const int w = tid >> 6;
  const int bid = blockIdx.x;
  const int g = bid & 15;
  const int m = bid >> 4;
  const int me = (g << 4) + m;
  if (NT <= 0) return;

  uint_t* flagsu = wsp;
  u64_t* flq = (u64_t*)wsp; // member slot: flq + me*16 (128B); 4 u64 used:
                            // [parity*2 + waveHalf] = {tag | csum<<32}
  uint_t* gbuf = wsp + GBUF_BASE;

  // ---- stage relu(x) as hi plane (s_pb) + lo plane (s_xlo) ----
  for (int i = tid; i < 1024; i += TPB) {
    int b = i >> 6, k0 = (i & 63) << 3;
    const float* px = x + (size_t)(g * NB + b) * 512 + k0;
    u32x4 vh, vl;
#pragma unroll
    for (int jj = 0; jj < 4; ++jj) {
      float f0 = px[2 * jj], f1 = px[2 * jj + 1];
      f0 = f0 > 0.f ? f0 : 0.f;
      f1 = f1 > 0.f ? f1 : 0.f;
      ushort_t h0 = bf16_rne(f0), h1 = bf16_rne(f1);
      vh[jj] = (uint_t)h0 | ((uint_t)h1 << 16);
      vl[jj] = (uint_t)bf16_rne(f0 - bf16f(h0)) |
               ((uint_t)bf16_rne(f1 - bf16f(h1)) << 16);
    }
    int c = k0 >> 5, kk = k0 & 31;
    int base = c * 1024 + ((((b << 6) + (kk << 1))) ^ ((b & 7) << 4));
    *(u32x4*)((char*)s_pb + base) = vh;
    *(u32x4*)((char*)s_xlo + base) = vl;
  }
  if (tid < NJ) s_bhh[tid] = bhh[1024 + m * NJ + tid];
  if (tid == 0) s_stop = 0;
  __syncthreads();

  short8 wA[16], wB[16];
  const f32x4 vzero = {0.f, 0.f, 0.f, 0.f};
  const int bcol = lane & 15;
  const int roff = ((bcol << 6) + ((lane >> 4) << 4)) ^ ((bcol & 7) << 4);
  const char* pb = (const char*)s_pb;
  const char* pxl = (const char*)s_xlo;

  // ---- gi = relu(x) @ W_ih^T (3-term hi/lo split) ----
  f32x4 acc0 = vzero, acc1 = vzero;
  if (w < 3) {
    loadW<false>(wA, Wih, 2 * w, m, lane);
    loadW<false>(wB, Wih, 2 * w + 1, m, lane);
    {
      f32x4 a0h = vzero, a0l = vzero, a1h = vzero, a1l = vzero;
#pragma unroll
      for (int c = 0; c < 16; ++c) {
        short8 bh = *(const short8*)(pb + c * 1024 + roff);
        short8 bl = *(const short8*)(pxl + c * 1024 + roff);
        a0h = __builtin_amdgcn_mfma_f32_16x16x32_bf16(wA[c], bh, a0h, 0, 0, 0);
        a1h = __builtin_amdgcn_mfma_f32_16x16x32_bf16(wB[c], bh, a1h, 0, 0, 0);
        a0l = __builtin_amdgcn_mfma_f32_16x16x32_bf16(wA[c], bl, a0l, 0, 0, 0);
        a1l = __builtin_amdgcn_mfma_f32_16x16x32_bf16(wB[c], bl, a1l, 0, 0, 0);
      }
      acc0 = a0h + a0l;
      acc1 = a1h + a1l;
    }
    loadW<true>(wA, Wih, 2 * w, m, lane);
    loadW<true>(wB, Wih, 2 * w + 1, m, lane);
#pragma unroll
    for (int c = 0; c < 16; ++c) {
      short8 bh = *(const short8*)(pb + c * 1024 + roff);
      acc0 = __builtin_amdgcn_mfma_f32_16x16x32_bf16(wA[c], bh, acc0, 0, 0, 0);
      acc1 = __builtin_amdgcn_mfma_f32_16x16x32_bf16(wB[c], bh, acc1, 0, 0, 0);
    }
  }
  __syncthreads();
  if (w < 3) {
    int drow = (lane >> 4) << 2;
#pragma unroll
    for (int q = 0; q < 4; ++q) {
      int rs0 = 2 * w * 16 + drow + q, rs1 = rs0 + 16;
      int g0 = gRow(rs0, m), g1 = gRow(rs1, m);
      s_gi[rs0 * 17 + bcol] = acc0[q] + bih[g0] + (rs0 < 64 ? bhh[g0] : 0.f);
      s_gi[rs1 * 17 + bcol] = acc1[q] + bih[g1] + (rs1 < 64 ? bhh[g1] : 0.f);
    }
    loadW<false>(wA, Whh, 2 * w, m, lane); // W_hh resident from here
    loadW<false>(wB, Whh, 2 * w + 1, m, lane);
  }
  for (int i = tid; i < 4096; i += TPB) s_pb[i] = 0u; // h0 = 0
  for (int i = tid; i < NB * NJ; i += TPB) s_hloc[i] = 0.f;
  __syncthreads();

  const size_t outRow = (size_t)NT * 512;
  float* outBase = out + (size_t)(g * NB) * outRow + m * NJ;

  for (int t = 0; t < NT; ++t) {
    const int par = (t + 1) & 1;
    // ---- phase 1: gh = W_hh @ h_hi from LDS chunks (waves 0-2) ----
    if (w < 3) {
      f32x4 aE0 = vzero, aO0 = vzero, aE1 = vzero, aO1 = vzero;
#pragma unroll
      for (int p = 0; p < 16; p += 2) {
        short8 b0 = *(const short8*)(pb + p * 1024 + roff);
        short8 b1 = *(const short8*)(pb + (p + 1) * 1024 + roff);
        aE0 = __builtin_amdgcn_mfma_f32_16x16x32_bf16(wA[p], b0, aE0, 0, 0, 0);
        aE1 = __builtin_amdgcn_mfma_f32_16x16x32_bf16(wB[p], b0, aE1, 0, 0, 0);
        aO0 = __builtin_amdgcn_mfma_f32_16x16x32_bf16(wA[p + 1], b1, aO0, 0, 0, 0);
        aO1 = __builtin_amdgcn_mfma_f32_16x16x32_bf16(wB[p + 1], b1, aO1, 0, 0, 0);
      }
      f32x4 r0 = aE0 + aO0, r1 = aE1 + aO1;
      int drow = (lane >> 4) << 2;
#pragma unroll
      for (int q = 0; q < 4; ++q) {
        s_gh[(2 * w * 16 + drow + q) * 17 + bcol] = r0[q];
        s_gh[((2 * w + 1) * 16 + drow + q) * 17 + bcol] = r1[q];
      }
    }
    __syncthreads();

    // ---- waves 4-5: gates, export, csum-flag (no drain!), out store ----
    const int et = tid - 256;
    if (et >= 0) {
      int b = et >> 3, j0 = (et & 7) << 2;
      float hn[4];
#pragma unroll
      for (int e = 0; e < 4; ++e) {
        int j = j0 + e;
        float pr = s_gi[j * 17 + b] + s_gh[j * 17 + b];
        float pz = s_gi[(32 + j) * 17 + b] + s_gh[(32 + j) * 17 + b];
        float r = 1.f / (1.f + __expf(-pr));
        float z = 1.f / (1.f + __expf(-pz));
        float pn =
            s_gi[(64 + j) * 17 + b] + r * (s_gh[(64 + j) * 17 + b] + s_bhh[j]);
        float n = 1.f - 2.f / (1.f + __expf(2.f * pn));
        hn[e] = n + z * (s_hloc[b * 32 + j] - n);
        s_hloc[b * 32 + j] = hn[e];
      }
      uint_t w0 = (uint_t)bf16_rne(hn[0]) | ((uint_t)bf16_rne(hn[1]) << 16);
      uint_t w1 = (uint_t)bf16_rne(hn[2]) | ((uint_t)bf16_rne(hn[3]) << 16);
      u64_t pq = (u64_t)w0 | ((u64_t)w1 << 32);
      u64_t* eb64 = (u64_t*)(gbuf + (size_t)par * BUF_U32 + g * GRP_U32);
      AST(eb64 + (m << 7) + (b << 3) + (et & 7), pq);
      uint_t c32 = fold64(pq); // wave-wide XOR csum of this wave's 64 u64s
#pragma unroll
      for (int off = 1; off < 64; off <<= 1) c32 ^= __shfl_xor(c32, off);
      if (lane == 0) {
        u64_t f = (u64_t)(uint_t)(t + 1) | ((u64_t)c32 << 32);
        AST(flq + ((size_t)me << 4) + (par << 1) + (w - 4), f);
      }
      f32x4 ov = {hn[0], hn[1], hn[2], hn[3]};
      __builtin_nontemporal_store(
          ov, (f32x4*)(outBase + (size_t)b * outRow + (size_t)t * 512 + j0));
    }

    // ---- waves 0-3: poll tags, reload, verify csum, write LDS ----
    if (w < 4 && t + 1 < NT) {
      const uint_t tgt = (uint_t)(t + 1);
      int aborted = 0;
      uint_t cs = 0;
      {
        const u64_t* fq =
            flq + ((size_t)((g << 4) + (w << 2) + (lane & 3)) << 4) +
            (par << 1);
        uint_t sp = 0;
        for (;;) {
          int rdy = 1;
          u64_t f0 = 0, f1 = 0;
          if (lane < 4) {
            f0 = ALD(fq);
            f1 = ALD(fq + 1);
            rdy = ((uint_t)f0 == tgt) && ((uint_t)f1 == tgt);
          }
          if (__all(rdy)) {
            cs = (uint_t)(f0 >> 32) ^ (uint_t)(f1 >> 32);
            break;
          }
          ++sp;
          uint_t ab = 0;
          if ((sp & 7u) == 0u) {
            ab = ALD(&flagsu[ABORT_IDX]);
            if (sp > POLL_MAX) {
              AST(&flagsu[ABORT_IDX], 1u);
              ab = 1;
            }
          }
          if (__any((int)(ab != 0))) {
            if (lane == 0) s_stop = 1;
            aborted = 1;
            break;
          }
          __builtin_amdgcn_s_sleep(1);
        }
      }
      if (!aborted) {
        const u64_t* srcq =
            (const u64_t*)(gbuf + (size_t)par * BUF_U32 + g * GRP_U32) +
            (w << 9);
        uint_t att = 0;
        int good = 0;
        u64_t q0, q1, q2, q3, q4, q5, q6, q7;
        for (;;) {
          q0 = ALD(srcq + lane + 0 * 64);
          q1 = ALD(srcq + lane + 1 * 64);
          q2 = ALD(srcq + lane + 2 * 64);
          q3 = ALD(srcq + lane + 3 * 64);
          q4 = ALD(srcq + lane + 4 * 64);
          q5 = ALD(srcq + lane + 5 * 64);
          q6 = ALD(srcq + lane + 6 * 64);
          q7 = ALD(srcq + lane + 7 * 64);
          uint_t c0 = fold64(q0 ^ q1), c1 = fold64(q2 ^ q3);
          uint_t c2 = fold64(q4 ^ q5), c3 = fold64(q6 ^ q7);
#pragma unroll
          for (int off = 1; off < 64; off <<= 1) {
            c0 ^= __shfl_xor(c0, off);
            c1 ^= __shfl_xor(c1, off);
            c2 ^= __shfl_xor(c2, off);
            c3 ^= __shfl_xor(c3, off);
          }
          uint_t mysum =
              (lane & 2) ? ((lane & 1) ? c3 : c2) : ((lane & 1) ? c1 : c0);
          int ok = (lane < 4) ? (mysum == cs) : 1;
          if (__all(ok)) {
            good = 1;
            break;
          }
          if (++att > VERIFY_MAX) {
            AST(&flagsu[ABORT_IDX], 1u);
            if (lane == 0) s_stop = 1;
            break;
          }
        }
        if (good) {
#define STI(k, qq)                                                             \
  {                                                                            \
    uint_t qb = (uint_t)(((w << 9) + lane + ((k) << 6)) << 3);                 \
    *(u64_t*)((char*)s_pb + (qb ^ (((qb >> 6) & 7u) << 4))) = (qq);            \
  }
          STI(0, q0) STI(1, q1) STI(2, q2) STI(3, q3)
          STI(4, q4) STI(5, q5) STI(6, q6) STI(7, q7)
#undef STI
        }
      }
    }
    __syncthreads();
    if (s_stop) break;
  }
}

extern "C" void kernel_launch(void* const* d_in, const int* in_sizes, int n_in,
                              void* d_out, int out_size, void* d_ws,
                              size_t ws_size, hipStream_t stream) {
  const float* x = (const float*)d_in[0];
  const float* Wih = (const float*)d_in[1];
  const float* Whh = (const float*)d_in[2];
  const float* bih = (const float*)d_in[3];
  const float* bhh = (const float*)d_in[4];
  float* out = (float*)d_out;
  int NT = out_size / (256 * 512);
  // ws: [0,32KB) csum-flag slots (128B/member) + abort @32KB;
  // data @64KB: 2 parities x 256KB (hi-plane h exchange).
  uint_t* wsp = (uint_t*)d_ws;
  (void)hipMemsetAsync(d_ws, 0, 65536, stream);
  hipLaunchKernelGGL(gru_kernel, dim3(NG * NM), dim3(TPB), 0, stream, x, Wih,
                     Whh, bih, bhh, out, wsp, NT);
}